// Round 5
// baseline (90.218 us; speedup 1.0000x reference)
//
#include <hip/hip_runtime.h>

// SmoothnessLoss: smooth[i] = sum_{j<64} |x[i+j] - mean_j(x[i+j])| for both inputs,
// out = mean((smoothHat - smoothY)^2) over W = N-k-1 windows. k fixed at 64.
//
// R5: wave-split arrays. R2/R4 held TWO e[68] register buffers (~160-200 VGPR ->
// 2 waves/SIMD occupancy cap, latency-bound at ~18.5us vs ~4us VALU floor).
// Now threads 0..127 process yHat, 128..255 process y: ONE e[68]/thread (~90 VGPR,
// capped <=128 via __launch_bounds__(256,4) -> >=4 waves/SIMD), and 2x wave count
// (7812 vs 3906) for latency hiding. Halves exchange smoothness via b128 LDS.
// HARD-WON (R3): e[] register promotion needs straight-line fully-unrolled code
// with constant e[] indices; runtime-indexed PRIVATE arrays / unroll-1 outer
// loops demote to per-use ds_read_b32 + stride-4 bank conflicts. The ds base
// address being runtime (branchless select of two fixed LDS arrays) is fine.

#define K     64
#define C     4                  // windows per thread
#define HALF  128                // threads per array
#define BLK   (2 * HALF)
#define WPB   (HALF * C)         // 512 windows per block
#define TILE  (WPB + K)          // 576 floats staged per array
#define TILE4 (TILE / 4)         // 144 float4 per array

__device__ __forceinline__ void windows_saod(const float* s, int o, float outd[C]) {
    float e[K + C];              // 68 floats -> VGPRs (constant indices, full unroll)
    const float4* p = (const float4*)(s + o);   // o = 4*(tid&127) -> 16B-aligned b128
    #pragma unroll
    for (int i = 0; i < (K + C) / 4; ++i) {
        float4 t = p[i];
        e[4 * i + 0] = t.x; e[4 * i + 1] = t.y;
        e[4 * i + 2] = t.z; e[4 * i + 3] = t.w;
    }
    float a0 = 0.f, a1 = 0.f, a2 = 0.f, a3 = 0.f;
    #pragma unroll
    for (int j = 0; j < K; j += 4) {
        a0 += e[j + 0]; a1 += e[j + 1]; a2 += e[j + 2]; a3 += e[j + 3];
    }
    float sums[C];
    sums[0] = (a0 + a1) + (a2 + a3);
    #pragma unroll
    for (int c = 1; c < C; ++c)
        sums[c] = sums[c - 1] + (e[K + c - 1] - e[c - 1]);

    #pragma unroll
    for (int c = 0; c < C; ++c) {
        const float m = sums[c] * (1.0f / K);
        float d0 = 0.f, d1 = 0.f, d2 = 0.f, d3 = 0.f;
        #pragma unroll
        for (int j = 0; j < K; j += 4) {
            d0 += fabsf(e[c + j + 0] - m);
            d1 += fabsf(e[c + j + 1] - m);
            d2 += fabsf(e[c + j + 2] - m);
            d3 += fabsf(e[c + j + 3] - m);
        }
        outd[c] = (d0 + d1) + (d2 + d3);
    }
}

__global__ __launch_bounds__(BLK, 4) void smoothness_loss_kernel(
    const float* __restrict__ yHat, const float* __restrict__ y,
    float* __restrict__ out, int N, int W, float invW)
{
    __shared__ __align__(16) float sA[TILE];     // 2.25 KB
    __shared__ __align__(16) float sB[TILE];
    __shared__ __align__(16) float4 xch[HALF];   // 2 KB: y-half's d[] -> yHat-half
    __shared__ float wave_sums[BLK / 64];

    const int base = blockIdx.x * WPB;           // multiple of 512 -> float4-aligned
    const int tid  = threadIdx.x;

    // Stage 144 float4 per array (288 total) with 256 threads, 2 rounds.
    // N % 4 == 0: a float4 is fully in-bounds or fully out (zero-fill).
    const float4* gA = (const float4*)(yHat + base);
    const float4* gB = (const float4*)(y + base);
    const int g4max = (N - base) / 4;
    #pragma unroll
    for (int r = 0; r < 2; ++r) {
        const int idx = tid + r * BLK;
        if (idx < 2 * TILE4) {
            const bool isB = (idx >= TILE4);
            const int pos  = isB ? (idx - TILE4) : idx;
            float4 v = make_float4(0.f, 0.f, 0.f, 0.f);
            if (pos < g4max) v = isB ? gB[pos] : gA[pos];
            float4* dst = isB ? (float4*)sB : (float4*)sA;
            dst[pos] = v;
        }
    }
    __syncthreads();

    const int half = tid >> 7;                   // 0: yHat, 1: y
    const int lt   = tid & (HALF - 1);
    const int o    = lt * C;                     // 16B-aligned local offset
    const float* s = half ? sB : sA;             // branchless select of fixed bases

    float d[C];
    windows_saod(s, o, d);                       // ONE e[68] live per thread

    float part = 0.f;
    if (half) {
        xch[lt] = make_float4(d[0], d[1], d[2], d[3]);   // b128 write
    }
    __syncthreads();
    if (!half) {
        const float4 db = xch[lt];               // b128 read
        const float dBv[C] = {db.x, db.y, db.z, db.w};
        const int w0 = base + o;
        #pragma unroll
        for (int c = 0; c < C; ++c) {
            if (w0 + c < W) {
                const float diff = d[c] - dBv[c];
                part += diff * diff;
            }
        }
    }

    // full-block reduction (half1 contributes 0)
    #pragma unroll
    for (int off = 32; off > 0; off >>= 1)
        part += __shfl_down(part, off, 64);

    const int lane = tid & 63;
    const int wv   = tid >> 6;
    if (lane == 0) wave_sums[wv] = part;
    __syncthreads();

    if (tid == 0) {
        float ssum = 0.f;
        #pragma unroll
        for (int i = 0; i < BLK / 64; ++i) ssum += wave_sums[i];
        atomicAdd(out, ssum * invW);
    }
}

extern "C" void kernel_launch(void* const* d_in, const int* in_sizes, int n_in,
                              void* d_out, int out_size, void* d_ws, size_t ws_size,
                              hipStream_t stream) {
    const float* yHat = (const float*)d_in[0];
    const float* y    = (const float*)d_in[1];
    float* out        = (float*)d_out;

    const int N = in_sizes[0];     // 1,000,000
    const int W = N - K - 1;       // 999,935
    const float invW = 1.0f / (float)W;

    hipMemsetAsync(out, 0, sizeof(float), stream);  // d_out re-poisoned each call

    const int grid = (W + WPB - 1) / WPB;           // 1954 blocks
    smoothness_loss_kernel<<<grid, BLK, 0, stream>>>(yHat, y, out, N, W, invW);
}

// Round 6
// 89.740 us; speedup vs baseline: 1.0053x; 1.0053x over previous
//
#include <hip/hip_runtime.h>

// SmoothnessLoss: smooth[i] = sum_{j<64} |x[i+j] - mean_j(x[i+j])| for both inputs,
// out = mean((smoothHat - smoothY)^2) over W = N-k-1 windows. k fixed at 64.
//
// R6: wave-split arrays + DIRECT GLOBAL loads (no LDS staging at all).
//  - waves 0-1 of each block process yHat, waves 2-3 process y -> ONE e[68]
//    register window per thread (~95 VGPR natural). NO forced occupancy cap:
//    R5's __launch_bounds__(256,4) (<=128 VGPR) caused scratch spills (+14us).
//  - inputs are 8 MB total -> fully L2-resident, wave-overlapping spans mostly
//    L1-resident. 17 x global_load_dwordx4/thread: lanes stride 16B -> each
//    wave-instruction is one contiguous 1KB transaction. Kills staging loop,
//    2 of 3 barriers, and the 4.25x LDS round-trip.
// HARD-WON (R3): e[68] promotion needs straight-line fully-unrolled code with
// constant private-array indices. Runtime base POINTERS are fine; runtime
// private indices / unroll-1 outer loops are not.

#define K     64
#define C     4                  // windows per thread
#define HALF  128                // threads per array half
#define BLK   (2 * HALF)
#define WPB   (HALF * C)         // 512 windows per block
#define NLD   ((K + C) / 4)      // 17 float4 loads per thread

__global__ __launch_bounds__(BLK) void smoothness_loss_kernel(
    const float* __restrict__ yHat, const float* __restrict__ y,
    float* __restrict__ out, int N, int W, float invW)
{
    __shared__ __align__(16) float4 xch[HALF];   // y-half's d[] -> yHat-half (2 KB)
    __shared__ float wave_sums[BLK / 64];

    const int base = blockIdx.x * WPB;           // multiple of 512 floats
    const int tid  = threadIdx.x;
    const int half = tid >> 7;                   // wave-uniform: 0=yHat, 1=y
    const int lt   = tid & (HALF - 1);
    const int w0   = base + lt * C;

    const float* g   = half ? y : yHat;          // scalar select (wave-uniform)
    const int    f0  = (base >> 2) + lt;         // first float4 index (16B-aligned)
    const float4* p  = (const float4*)g + f0;

    // Load 68-float window straight into registers.
    float e[K + C];
    const bool safe = (base + WPB + K) <= N;     // block-uniform; true for N=1e6
    if (safe) {
        #pragma unroll
        for (int j = 0; j < NLD; ++j) {
            float4 t = p[j];
            e[4 * j + 0] = t.x; e[4 * j + 1] = t.y;
            e[4 * j + 2] = t.z; e[4 * j + 3] = t.w;
        }
    } else {
        const int fmax = N >> 2;                 // N % 4 == 0
        #pragma unroll
        for (int j = 0; j < NLD; ++j) {
            float4 t = make_float4(0.f, 0.f, 0.f, 0.f);
            if (f0 + j < fmax) t = p[j];
            e[4 * j + 0] = t.x; e[4 * j + 1] = t.y;
            e[4 * j + 2] = t.z; e[4 * j + 3] = t.w;
        }
    }

    // window-0 sum: 4 independent partials
    float a0 = 0.f, a1 = 0.f, a2 = 0.f, a3 = 0.f;
    #pragma unroll
    for (int j = 0; j < K; j += 4) {
        a0 += e[j + 0]; a1 += e[j + 1]; a2 += e[j + 2]; a3 += e[j + 3];
    }
    float sums[C];
    sums[0] = (a0 + a1) + (a2 + a3);
    #pragma unroll
    for (int c = 1; c < C; ++c)
        sums[c] = sums[c - 1] + (e[K + c - 1] - e[c - 1]);

    // abs-dev per window (fabs folds into v_add src modifier)
    float d[C];
    #pragma unroll
    for (int c = 0; c < C; ++c) {
        const float m = sums[c] * (1.0f / K);
        float d0 = 0.f, d1 = 0.f, d2 = 0.f, d3 = 0.f;
        #pragma unroll
        for (int j = 0; j < K; j += 4) {
            d0 += fabsf(e[c + j + 0] - m);
            d1 += fabsf(e[c + j + 1] - m);
            d2 += fabsf(e[c + j + 2] - m);
            d3 += fabsf(e[c + j + 3] - m);
        }
        d[c] = (d0 + d1) + (d2 + d3);
    }

    // y-half hands its smoothness to the yHat-half; one barrier total
    float part = 0.f;
    if (half) xch[lt] = make_float4(d[0], d[1], d[2], d[3]);
    __syncthreads();
    if (!half) {
        const float4 db = xch[lt];
        const float dB[C] = {db.x, db.y, db.z, db.w};
        #pragma unroll
        for (int c = 0; c < C; ++c) {
            if (w0 + c < W) {
                const float diff = d[c] - dB[c];
                part += diff * diff;
            }
        }
    }

    // wave-64 shuffle reduction -> per-wave LDS -> one atomic per block
    #pragma unroll
    for (int off = 32; off > 0; off >>= 1)
        part += __shfl_down(part, off, 64);

    const int lane = tid & 63;
    const int wv   = tid >> 6;
    if (lane == 0) wave_sums[wv] = part;
    __syncthreads();

    if (tid == 0) {
        float ssum = 0.f;
        #pragma unroll
        for (int i = 0; i < BLK / 64; ++i) ssum += wave_sums[i];
        atomicAdd(out, ssum * invW);
    }
}

extern "C" void kernel_launch(void* const* d_in, const int* in_sizes, int n_in,
                              void* d_out, int out_size, void* d_ws, size_t ws_size,
                              hipStream_t stream) {
    const float* yHat = (const float*)d_in[0];
    const float* y    = (const float*)d_in[1];
    float* out        = (float*)d_out;

    const int N = in_sizes[0];     // 1,000,000
    const int W = N - K - 1;       // 999,935
    const float invW = 1.0f / (float)W;

    hipMemsetAsync(out, 0, sizeof(float), stream);  // d_out re-poisoned each call

    const int grid = (W + WPB - 1) / WPB;           // 1953 blocks
    smoothness_loss_kernel<<<grid, BLK, 0, stream>>>(yHat, y, out, N, W, invW);
}

// Round 7
// 77.735 us; speedup vs baseline: 1.1606x; 1.1544x over previous
//
#include <hip/hip_runtime.h>

// SmoothnessLoss: smooth[i] = sum_{j<64} |x[i+j] - mean_j(x[i+j])| for both inputs,
// out = mean((smoothHat - smoothY)^2) over W = N-k-1 windows. k fixed at 64.
//
// R7: wave-split + C=8 + direct global loads.
//  - C=8 windows/thread: load amplification (K+C)/C drops 17x -> 9x (72 MB vs
//    136 MB through L1/L2) and load wave-instrs halve vs R6.
//  - wave-split (waves 0-1: yHat, waves 2-3: y) keeps ONE e[72] buffer live
//    (~110 VGPR natural, no __launch_bounds__ cap -- R5's cap caused spills).
//  - grid back to 977 blocks / 3906 waves == R4's shape (best run so far).
//  - base pointer forced to SGPR via readfirstlane (half is wave-uniform).
// HARD-WON (R3): e[] register promotion needs fully-unrolled code with constant
// private-array indices; runtime private indices demote to scratch/LDS.

#define K     64
#define C     8                  // windows per thread
#define HALF  128                // threads per array half
#define BLK   (2 * HALF)
#define WPB   (HALF * C)         // 1024 windows per block
#define NLD   ((K + C) / 4)      // 18 float4 loads per thread (e[72])

__global__ __launch_bounds__(BLK) void smoothness_loss_kernel(
    const float* __restrict__ yHat, const float* __restrict__ y,
    float* __restrict__ out, int N, int W, float invW)
{
    __shared__ __align__(16) float4 xch[2 * HALF];  // y-half's d[8] per thread (4 KB)
    __shared__ float wave_sums[BLK / 64];

    const int base = blockIdx.x * WPB;           // multiple of 1024 floats
    const int tid  = threadIdx.x;
    const int half = __builtin_amdgcn_readfirstlane(tid >> 7);  // wave-uniform
    const int lt   = tid & (HALF - 1);
    const int w0   = base + lt * C;

    const float* g  = half ? y : yHat;           // SGPR base select
    const int    f0 = (base >> 2) + 2 * lt;      // first float4 idx (32B-aligned)
    const float4* p = (const float4*)g + f0;

    // Load 72-float window straight into registers (18 coalesced dwordx4).
    float e[K + C];
    const bool safe = (base + WPB + K) <= N;     // block-uniform
    if (safe) {
        #pragma unroll
        for (int j = 0; j < NLD; ++j) {
            float4 t = p[j];
            e[4 * j + 0] = t.x; e[4 * j + 1] = t.y;
            e[4 * j + 2] = t.z; e[4 * j + 3] = t.w;
        }
    } else {
        const int fmax = N >> 2;                 // N % 4 == 0
        #pragma unroll
        for (int j = 0; j < NLD; ++j) {
            float4 t = make_float4(0.f, 0.f, 0.f, 0.f);
            if (f0 + j < fmax) t = p[j];         // zero-fill: only discarded
            e[4 * j + 0] = t.x; e[4 * j + 1] = t.y;   // windows (>=W) touch it
            e[4 * j + 2] = t.z; e[4 * j + 3] = t.w;
        }
    }

    // window-0 sum: 4 independent partials
    float a0 = 0.f, a1 = 0.f, a2 = 0.f, a3 = 0.f;
    #pragma unroll
    for (int j = 0; j < K; j += 4) {
        a0 += e[j + 0]; a1 += e[j + 1]; a2 += e[j + 2]; a3 += e[j + 3];
    }
    float sums[C];
    sums[0] = (a0 + a1) + (a2 + a3);
    #pragma unroll
    for (int c = 1; c < C; ++c)
        sums[c] = sums[c - 1] + (e[K + c - 1] - e[c - 1]);

    // abs-dev per window (fabs folds into src modifier)
    float d[C];
    #pragma unroll
    for (int c = 0; c < C; ++c) {
        const float m = sums[c] * (1.0f / K);
        float d0 = 0.f, d1 = 0.f, d2 = 0.f, d3 = 0.f;
        #pragma unroll
        for (int j = 0; j < K; j += 4) {
            d0 += fabsf(e[c + j + 0] - m);
            d1 += fabsf(e[c + j + 1] - m);
            d2 += fabsf(e[c + j + 2] - m);
            d3 += fabsf(e[c + j + 3] - m);
        }
        d[c] = (d0 + d1) + (d2 + d3);
    }

    // y-half hands its 8 smoothness values to the yHat-half
    float part = 0.f;
    if (half) {
        xch[2 * lt + 0] = make_float4(d[0], d[1], d[2], d[3]);
        xch[2 * lt + 1] = make_float4(d[4], d[5], d[6], d[7]);
    }
    __syncthreads();
    if (!half) {
        const float4 b0 = xch[2 * lt + 0];
        const float4 b1 = xch[2 * lt + 1];
        const float dB[C] = {b0.x, b0.y, b0.z, b0.w, b1.x, b1.y, b1.z, b1.w};
        #pragma unroll
        for (int c = 0; c < C; ++c) {
            if (w0 + c < W) {
                const float diff = d[c] - dB[c];
                part += diff * diff;
            }
        }
    }

    // wave-64 shuffle reduction -> per-wave LDS -> one atomic per block
    #pragma unroll
    for (int off = 32; off > 0; off >>= 1)
        part += __shfl_down(part, off, 64);

    const int lane = tid & 63;
    const int wv   = tid >> 6;
    if (lane == 0) wave_sums[wv] = part;
    __syncthreads();

    if (tid == 0) {
        float ssum = 0.f;
        #pragma unroll
        for (int i = 0; i < BLK / 64; ++i) ssum += wave_sums[i];
        atomicAdd(out, ssum * invW);
    }
}

extern "C" void kernel_launch(void* const* d_in, const int* in_sizes, int n_in,
                              void* d_out, int out_size, void* d_ws, size_t ws_size,
                              hipStream_t stream) {
    const float* yHat = (const float*)d_in[0];
    const float* y    = (const float*)d_in[1];
    float* out        = (float*)d_out;

    const int N = in_sizes[0];     // 1,000,000
    const int W = N - K - 1;       // 999,935
    const float invW = 1.0f / (float)W;

    hipMemsetAsync(out, 0, sizeof(float), stream);  // d_out re-poisoned each call

    const int grid = (W + WPB - 1) / WPB;           // 977 blocks
    smoothness_loss_kernel<<<grid, BLK, 0, stream>>>(yHat, y, out, N, W, invW);
}

// Round 8
// 71.739 us; speedup vs baseline: 1.2576x; 1.0836x over previous
//
#include <hip/hip_runtime.h>

// SmoothnessLoss: smooth[i] = sum_{j<64} |x[i+j] - mean_j(x[i+j])| for both inputs,
// out = mean((smoothHat - smoothY)^2) over W = N-k-1 windows. k fixed at 64.
//
// R8 = R7 compute + NO same-address atomics.
// THEORY (fits R1-R7 with one parameter): blocks finish in synchronized bursts
// and all atomicAdd the SAME fp32 address -> serialized L2 RMW ~29cyc each.
// 3906 atomics = 47us (R1), 1954 = 24us (R5/R6), 977 = 12us (R2/R4/R7) --
// the entire inter-round plateau. Fix: per-block store to distinct d_ws slot
// (zero contention) + tiny second reduction kernel writing out[0] (pure store,
// so the d_out memset dispatch is dropped as well).
// HARD-WON (R3): e[] register promotion needs fully-unrolled code with constant
// private-array indices. R5: forced __launch_bounds__ occupancy caps -> spills.

#define K     64
#define C     8                  // windows per thread
#define HALF  128                // threads per array half
#define BLK   (2 * HALF)
#define WPB   (HALF * C)         // 1024 windows per block
#define NLD   ((K + C) / 4)      // 18 float4 loads per thread (e[72])

__global__ __launch_bounds__(BLK) void smoothness_partial_kernel(
    const float* __restrict__ yHat, const float* __restrict__ y,
    float* __restrict__ ws, int N, int W)
{
    __shared__ __align__(16) float4 xch[2 * HALF];  // y-half's d[8] per thread (4 KB)
    __shared__ float wave_sums[BLK / 64];

    const int base = blockIdx.x * WPB;           // multiple of 1024 floats
    const int tid  = threadIdx.x;
    const int half = __builtin_amdgcn_readfirstlane(tid >> 7);  // wave-uniform
    const int lt   = tid & (HALF - 1);
    const int w0   = base + lt * C;

    const float* g  = half ? y : yHat;           // SGPR base select
    const int    f0 = (base >> 2) + 2 * lt;      // first float4 idx (32B-aligned)
    const float4* p = (const float4*)g + f0;

    // Load 72-float window straight into registers (18 coalesced dwordx4).
    float e[K + C];
    const bool safe = (base + WPB + K) <= N;     // block-uniform
    if (safe) {
        #pragma unroll
        for (int j = 0; j < NLD; ++j) {
            float4 t = p[j];
            e[4 * j + 0] = t.x; e[4 * j + 1] = t.y;
            e[4 * j + 2] = t.z; e[4 * j + 3] = t.w;
        }
    } else {
        const int fmax = N >> 2;                 // N % 4 == 0
        #pragma unroll
        for (int j = 0; j < NLD; ++j) {
            float4 t = make_float4(0.f, 0.f, 0.f, 0.f);
            if (f0 + j < fmax) t = p[j];         // zero-fill: only discarded
            e[4 * j + 0] = t.x; e[4 * j + 1] = t.y;   // windows (>=W) touch it
            e[4 * j + 2] = t.z; e[4 * j + 3] = t.w;
        }
    }

    // window-0 sum: 4 independent partials
    float a0 = 0.f, a1 = 0.f, a2 = 0.f, a3 = 0.f;
    #pragma unroll
    for (int j = 0; j < K; j += 4) {
        a0 += e[j + 0]; a1 += e[j + 1]; a2 += e[j + 2]; a3 += e[j + 3];
    }
    float sums[C];
    sums[0] = (a0 + a1) + (a2 + a3);
    #pragma unroll
    for (int c = 1; c < C; ++c)
        sums[c] = sums[c - 1] + (e[K + c - 1] - e[c - 1]);

    // abs-dev per window (fabs folds into src modifier)
    float d[C];
    #pragma unroll
    for (int c = 0; c < C; ++c) {
        const float m = sums[c] * (1.0f / K);
        float d0 = 0.f, d1 = 0.f, d2 = 0.f, d3 = 0.f;
        #pragma unroll
        for (int j = 0; j < K; j += 4) {
            d0 += fabsf(e[c + j + 0] - m);
            d1 += fabsf(e[c + j + 1] - m);
            d2 += fabsf(e[c + j + 2] - m);
            d3 += fabsf(e[c + j + 3] - m);
        }
        d[c] = (d0 + d1) + (d2 + d3);
    }

    // y-half hands its 8 smoothness values to the yHat-half
    float part = 0.f;
    if (half) {
        xch[2 * lt + 0] = make_float4(d[0], d[1], d[2], d[3]);
        xch[2 * lt + 1] = make_float4(d[4], d[5], d[6], d[7]);
    }
    __syncthreads();
    if (!half) {
        const float4 b0 = xch[2 * lt + 0];
        const float4 b1 = xch[2 * lt + 1];
        const float dB[C] = {b0.x, b0.y, b0.z, b0.w, b1.x, b1.y, b1.z, b1.w};
        #pragma unroll
        for (int c = 0; c < C; ++c) {
            if (w0 + c < W) {
                const float diff = d[c] - dB[c];
                part += diff * diff;
            }
        }
    }

    // wave-64 shuffle reduction -> per-wave LDS -> ONE PLAIN STORE per block
    #pragma unroll
    for (int off = 32; off > 0; off >>= 1)
        part += __shfl_down(part, off, 64);

    const int lane = tid & 63;
    const int wv   = tid >> 6;
    if (lane == 0) wave_sums[wv] = part;
    __syncthreads();

    if (tid == 0) {
        float ssum = 0.f;
        #pragma unroll
        for (int i = 0; i < BLK / 64; ++i) ssum += wave_sums[i];
        ws[blockIdx.x] = ssum;                   // distinct address: no contention
    }
}

__global__ __launch_bounds__(256) void smoothness_final_kernel(
    const float* __restrict__ ws, float* __restrict__ out, int nb, float invW)
{
    __shared__ float wave_sums[4];
    const int tid = threadIdx.x;

    float s = 0.f;
    for (int i = tid; i < nb; i += 256) s += ws[i];

    #pragma unroll
    for (int off = 32; off > 0; off >>= 1)
        s += __shfl_down(s, off, 64);

    if ((tid & 63) == 0) wave_sums[tid >> 6] = s;
    __syncthreads();

    if (tid == 0) {
        float t = (wave_sums[0] + wave_sums[1]) + (wave_sums[2] + wave_sums[3]);
        out[0] = t * invW;                       // pure store: no d_out memset needed
    }
}

extern "C" void kernel_launch(void* const* d_in, const int* in_sizes, int n_in,
                              void* d_out, int out_size, void* d_ws, size_t ws_size,
                              hipStream_t stream) {
    const float* yHat = (const float*)d_in[0];
    const float* y    = (const float*)d_in[1];
    float* out        = (float*)d_out;
    float* ws         = (float*)d_ws;

    const int N = in_sizes[0];     // 1,000,000
    const int W = N - K - 1;       // 999,935
    const float invW = 1.0f / (float)W;

    const int grid = (W + WPB - 1) / WPB;           // 977 blocks
    smoothness_partial_kernel<<<grid, BLK, 0, stream>>>(yHat, y, ws, N, W);
    smoothness_final_kernel<<<1, 256, 0, stream>>>(ws, out, grid, invW);
}